// Round 8
// baseline (694.830 us; speedup 1.0000x reference)
//
#include <hip/hip_runtime.h>
#include <hip/hip_bf16.h>

#define G_ 256
#define K_ 16
#define L_ 3
#define H_ 3
#define F_ 64
#define EMB_ 200
#define HID_ 256
#define N_ (G_*K_)

typedef __attribute__((ext_vector_type(8))) short short8;
typedef __attribute__((ext_vector_type(4))) float f32x4;

#define SELU_S 1.0507009873554804934193349852946f
#define SELU_SA (1.0507009873554804934193349852946f*1.6732632423543772848170429916717f)
#define LOG2E_ 1.4426950408889634073599246810019f
#define SLN2_ (SELU_S*0.69314718055994530941723212145818f)

__device__ __forceinline__ float exp2_fast(float x) {
#if __has_builtin(__builtin_amdgcn_exp2f)
  return __builtin_amdgcn_exp2f(x);
#else
  return __exp2f(x);
#endif
}

// selu on t = x*log2(e); cry only (twice-measured regression in edge hot loops).
__device__ __forceinline__ float selu_t(float t) {
  float tn = fminf(t, 0.f), tp = fmaxf(t, 0.f);
  return fmaf(SELU_SA, exp2_fast(tn), fmaf(SLN2_, tp, -SELU_SA));
}

__device__ __forceinline__ float selu_f(float x) {
  float e = __expf(x);
  float neg = fmaf(SELU_SA, e, -SELU_SA);
  float pos = SELU_S * x;
  return x > 0.f ? pos : neg;
}

__device__ __forceinline__ unsigned short f2bf(float x) {
  __hip_bfloat16 h = __float2bfloat16(x);
  return *reinterpret_cast<unsigned short*>(&h);
}

__device__ __forceinline__ unsigned int f2bf2(float a, float b) {
  float2 t; t.x = a; t.y = b;
  __hip_bfloat162 h = __float22bfloat162_rn(t);
  return *reinterpret_cast<unsigned int*>(&h);
}

__device__ __forceinline__ float bf2f(unsigned short u) {
  union { unsigned int i; float f; } v;
  v.i = ((unsigned int)u) << 16;
  return v.f;
}

// 3-block-per-graph barrier. Safe: grid 768 <= co-resident capacity 1024
// (LDS 33.5KB -> 4 blk/CU, VGPR capped 64 via __launch_bounds__(512,8)),
// so all blocks are placed at launch and the spin always makes progress.
__device__ __forceinline__ void graph_barrier(unsigned int* c, int t) {
  __syncthreads();
  if (t == 0) {
    __threadfence();                       // release prior device-scope writes
    atomicAdd(c, 1u);
    while (__hip_atomic_load(c, __ATOMIC_ACQUIRE, __HIP_MEMORY_SCOPE_AGENT) < 3u)
      __builtin_amdgcn_s_sleep(8);
  }
  __syncthreads();
  __threadfence();                         // acquire: invalidate stale cache lines
}

// One kernel: blocks 256..1279 do init_embed (4 nodes each) then ALL 1280
// blocks grid-stride the weight transposes / bias folding / zeroing.
__global__ __launch_bounds__(256) void prep_init_all(
    const float* __restrict__ mg_W1, const float* __restrict__ mm_W1,
    const float* __restrict__ mm_W2, const float* __restrict__ cg_W1,
    const float* __restrict__ cm_W1, const float* __restrict__ cm_W2,
    const float* __restrict__ mg_b1, const float* __restrict__ mm_b1,
    const float* __restrict__ cg_b1, const float* __restrict__ cm_b1,
    unsigned short* __restrict__ WcatT, unsigned short* __restrict__ W2mT,
    unsigned short* __restrict__ WcryT, unsigned short* __restrict__ W2cT,
    float* __restrict__ bias_e, float* __restrict__ bias_c,
    float* __restrict__ out0, float* __restrict__ feaZ,
    const float* __restrict__ fea_in, const float* __restrict__ W_init,
    const float* __restrict__ b_init, const float* __restrict__ wts,
    float* __restrict__ feaA, unsigned int* __restrict__ cnt0) {
  int bid = blockIdx.x, tid = threadIdx.x;
  if (bid >= 256) {
    __shared__ float row[4][EMB_];
    int sub = tid >> 6, j = tid & 63;
    int n = (bid - 256) * 4 + sub;
    for (int k = j; k < EMB_; k += 64) row[sub][k] = fea_in[(size_t)n*EMB_ + k];
    __syncthreads();
    if (j < F_-1) {
      float s = b_init[j];
      for (int k = 0; k < EMB_; ++k) s = fmaf(row[sub][k], W_init[k*(F_-1) + j], s);
      feaA[(size_t)n*F_ + j] = s;
    } else {
      feaA[(size_t)n*F_ + (F_-1)] = wts[n];
    }
  }
  int gt = bid*256 + tid, GT = gridDim.x*256;
  for (int idx = gt; idx < 9*1024*64; idx += GT) {      // WcatT[lh][n][k]
    int lh = idx >> 16, n = (idx >> 6) & 1023, k = idx & 63;
    const float* W = (n < 512) ? mg_W1 : mm_W1;
    int nn = n & 511;
    int r = (nn < 256) ? k : (64 + k);
    WcatT[idx] = f2bf(W[(size_t)lh*(2*F_*HID_) + r*HID_ + (nn & 255)]);
  }
  for (int idx = gt; idx < 9*64*256; idx += GT) {       // W2mT[lh][f][k]
    int lh = idx >> 14, f = (idx >> 8) & 63, k = idx & 255;
    W2mT[idx] = f2bf(mm_W2[(size_t)lh*(HID_*F_) + k*F_ + f]);
  }
  for (int idx = gt; idx < 1536*64; idx += GT) {        // WcryT[n][k]
    int n = idx >> 6, k = idx & 63;
    int hh = n >> 9, r = n & 511;
    float v = (r < 256) ? cg_W1[(size_t)hh*F_*HID_ + k*HID_ + r]
                        : cm_W1[(size_t)hh*F_*HID_ + k*HID_ + (r - 256)];
    WcryT[idx] = f2bf(v);
  }
  for (int idx = gt; idx < 3*64*256; idx += GT) {       // W2cT[h][f][k]
    int hh = idx >> 14, f = (idx >> 8) & 63, k = idx & 255;
    W2cT[idx] = f2bf(cm_W2[(size_t)hh*HID_*F_ + k*F_ + f]);
  }
  for (int idx = gt; idx < 9216 + 1536 + G_*F_ + 1024; idx += GT) {
    if (idx < 9216) {
      int l = idx / 3072, c = idx - l*3072;
      int hh = c >> 10, cc = c & 1023;
      int lh = l*H_ + hh;
      float v = 0.f;
      if (cc < 256) v = mg_b1[lh*HID_ + cc];
      else if (cc >= 512 && cc < 768) v = mm_b1[lh*HID_ + (cc - 512)];
      bias_e[idx] = v;
    } else if (idx < 9216 + 1536) {
      int c = idx - 9216;
      int hh = c >> 9, cc = c & 511;
      bias_c[c] = (cc < 256) ? cg_b1[hh*HID_ + cc] : cm_b1[hh*HID_ + (cc - 256)];
    } else if (idx < 9216 + 1536 + G_*F_) {
      out0[idx - 9216 - 1536] = 0.f;
    } else {
      cnt0[idx - 9216 - 1536 - G_*F_] = 0u;             // graph barrier counters
    }
  }
  float4 z4; z4.x = 0.f; z4.y = 0.f; z4.z = 0.f; z4.w = 0.f;
  for (int idx = gt; idx < (3*N_*F_)/4; idx += GT)
    ((float4*)feaZ)[idx] = z4;
}

// Overlaid shared memory: edge phase (33.5KB) and cry phase (31.8KB).
struct EdgeSmem {
  unsigned short feaS[16][72];
  unsigned short PQs[16][520];
  unsigned short HbarS[16][264];
  float bs[512];
  float w2g[256];
  float gred[240][2];
  float gateA[240];
  float sumat[16];
  float wp[16];
};
struct CrySmem {
  unsigned short feaS[16][72];
  unsigned short PQh[16][520];
  unsigned short hidc[16][264];
  float bsc[512];
  float gred[16][36];
  float attnL[16];
  float sumatS;
};
union NetSmem { EdgeSmem e; CrySmem c; };

// One edge layer for head h of graph g (R5 proven bf16-PQ body).
__device__ __forceinline__ void do_layer(
    NetSmem& S, int t, int g16, int h, int l,
    const float* __restrict__ cur, float* __restrict__ nxt,
    const unsigned short* __restrict__ WcatT, const float* __restrict__ bias_e,
    const unsigned short* __restrict__ W2T, const float* __restrict__ mg_W2,
    const float* __restrict__ mg_b2, const float* __restrict__ m_pow,
    const float* __restrict__ mm_b2, const float* __restrict__ wts) {
  EdgeSmem& e = S.e;
  int lh = l*H_ + h;
  const unsigned short* Wlh = WcatT + (size_t)lh*1024*64;
  const float* biaslh = bias_e + (size_t)l*3072 + h*1024;
  int w = t >> 6, lane = t & 63, mr = lane & 15, q = lane >> 4;

  // P0: stage fea (bf16), gate bias, gate-W2
  {
    int row = t >> 5, c2 = (t & 31) * 2;
    float2 fv = *(const float2*)&cur[(size_t)(g16 + row)*64 + c2];
    *(unsigned int*)&e.feaS[row][c2] = f2bf2(fv.x, fv.y);
  }
  e.bs[t] = biaslh[t];
  if (t < 256) e.w2g[t] = mg_W2[lh*HID_ + t];
  __syncthreads();

  // P1: gate-half PQ GEMM
  {
    int n0w = w * 64;
    short8 a0 = *(const short8*)&e.feaS[mr][q*8];
    short8 a1 = *(const short8*)&e.feaS[mr][32 + q*8];
    #pragma unroll
    for (int nt = 0; nt < 4; ++nt) {
      int n = n0w + nt*16 + mr;
      const unsigned short* bp = Wlh + (size_t)n*64 + q*8;
      short8 b0 = *(const short8*)bp;
      short8 b1 = *(const short8*)(bp + 32);
      f32x4 z = {0.f, 0.f, 0.f, 0.f};
      z = __builtin_amdgcn_mfma_f32_16x16x32_bf16(a0, b0, z, 0, 0, 0);
      z = __builtin_amdgcn_mfma_f32_16x16x32_bf16(a1, b1, z, 0, 0, 0);
      float bb = e.bs[n];
      #pragma unroll
      for (int r = 0; r < 4; ++r)
        e.PQs[q*4 + r][n] = f2bf(z[r] + bb);
    }
  }
  __syncthreads();

  // P2: gate dot (480 thr) + wp + msg bias reload
  {
    float nb = biaslh[512 + t];
    if (t < 480) {
      int ed = t >> 1, half = t & 1;
      int i = ed / 15, jj = ed - i*15;
      int j = (jj < i) ? jj : jj + 1;
      float s = 0.f;
      #pragma unroll
      for (int u = 0; u < 16; ++u) {
        int c = half*8 + u*16;
        short8 pv = *(const short8*)&e.PQs[i][c];
        short8 qv = *(const short8*)&e.PQs[j][256 + c];
        #pragma unroll
        for (int r = 0; r < 8; ++r) {
          float hv = selu_f(bf2f((unsigned short)pv[r]) + bf2f((unsigned short)qv[r]));
          s = fmaf(hv, e.w2g[c + r], s);
        }
      }
      e.gred[ed][half] = s;
    } else if (t < 496) {
      e.wp[t - 480] = __powf(wts[g16 + (t - 480)], m_pow[lh]);
    }
    e.bs[t] = nb;
  }
  __syncthreads();

  // P3: msg-half PQ GEMM (overwrite PQs) + softmax (t<16)
  {
    int n0w = w * 64;
    short8 a0 = *(const short8*)&e.feaS[mr][q*8];
    short8 a1 = *(const short8*)&e.feaS[mr][32 + q*8];
    #pragma unroll
    for (int nt = 0; nt < 4; ++nt) {
      int n = n0w + nt*16 + mr;
      const unsigned short* bp = Wlh + (size_t)(512 + n)*64 + q*8;
      short8 b0 = *(const short8*)bp;
      short8 b1 = *(const short8*)(bp + 32);
      f32x4 z = {0.f, 0.f, 0.f, 0.f};
      z = __builtin_amdgcn_mfma_f32_16x16x32_bf16(a0, b0, z, 0, 0, 0);
      z = __builtin_amdgcn_mfma_f32_16x16x32_bf16(a1, b1, z, 0, 0, 0);
      float bb = e.bs[n];
      #pragma unroll
      for (int r = 0; r < 4; ++r)
        e.PQs[q*4 + r][n] = f2bf(z[r] + bb);
    }
  }
  if (t < 16) {
    int i = t;
    float b2v = mg_b2[lh];
    float gl[15];
    float m = -1e30f;
    #pragma unroll
    for (int jj = 0; jj < 15; ++jj) {
      float v = e.gred[i*15 + jj][0] + e.gred[i*15 + jj][1] + b2v;
      gl[jj] = v; m = fmaxf(m, v);
    }
    float den = 0.f;
    #pragma unroll
    for (int jj = 0; jj < 15; ++jj) {
      int j = (jj < i) ? jj : jj + 1;
      float x = e.wp[j] * __expf(gl[jj] - m);
      gl[jj] = x; den += x;
    }
    den += 1e-10f;
    float sa = 0.f;
    #pragma unroll
    for (int jj = 0; jj < 15; ++jj) {
      float a = gl[jj] / den; e.gateA[i*15 + jj] = a; sa += a;
    }
    e.sumat[i] = sa;
  }
  __syncthreads();

  // P4: Hbar[i][k] = sum_j attn*selu(P+Q); f32 accum, bf16 out
  {
    int i = t >> 5, k0 = (t & 31) * 8;
    short8 pv = *(const short8*)&e.PQs[i][k0];
    float pf[8];
    #pragma unroll
    for (int r = 0; r < 8; ++r) pf[r] = bf2f((unsigned short)pv[r]);
    float hb[8] = {0.f, 0.f, 0.f, 0.f, 0.f, 0.f, 0.f, 0.f};
    for (int jj = 0; jj < 15; ++jj) {
      int j = (jj < i) ? jj : jj + 1;
      float a = e.gateA[i*15 + jj];
      short8 qv = *(const short8*)&e.PQs[j][256 + k0];
      #pragma unroll
      for (int r = 0; r < 8; ++r) {
        float hv = selu_f(pf[r] + bf2f((unsigned short)qv[r]));
        hb[r] = fmaf(a, hv, hb[r]);
      }
    }
    unsigned int hpk[4];
    #pragma unroll
    for (int r2 = 0; r2 < 4; ++r2) hpk[r2] = f2bf2(hb[2*r2], hb[2*r2+1]);
    *(short8*)&e.HbarS[i][k0] = *reinterpret_cast<short8*>(hpk);
  }
  __syncthreads();

  // P5: Hbar @ W2m on waves 0..3; epilogue (+residual on h==0)
  if (w < 4) {
    const unsigned short* W2lh = W2T + (size_t)lh*64*256;
    f32x4 acc = {0.f, 0.f, 0.f, 0.f};
    #pragma unroll
    for (int kc = 0; kc < 8; ++kc) {
      short8 a = *(const short8*)&e.HbarS[mr][kc*32 + q*8];
      short8 b = *(const short8*)&W2lh[(size_t)(w*16 + mr)*256 + kc*32 + q*8];
      acc = __builtin_amdgcn_mfma_f32_16x16x32_bf16(a, b, acc, 0, 0, 0);
    }
    int f = w*16 + mr;
    float b2 = mm_b2[lh*F_ + f];
    #pragma unroll
    for (int r = 0; r < 4; ++r) {
      int i = q*4 + r;
      float val = (acc[r] + b2*e.sumat[i]) * (1.f/3.f);
      if (h == 0) val += cur[(size_t)(g16 + i)*64 + f];
      atomicAdd(&nxt[(size_t)(g16 + i)*64 + f], val);
    }
  }
}

// Crystal head h for graph g (512-thread adaptation, bf16 PQ).
__device__ __forceinline__ void do_cry(
    NetSmem& S, int t, int g, int h,
    const float* __restrict__ fea, const unsigned short* __restrict__ WcryT,
    const float* __restrict__ bias_c, const unsigned short* __restrict__ W2cT,
    const float* __restrict__ cg_W2, const float* __restrict__ cg_b2,
    const float* __restrict__ cm_b2, const float* __restrict__ c_pow,
    const float* __restrict__ wts, float* __restrict__ out) {
  CrySmem& c = S.c;
  int g16 = g*16;
  int w = t >> 6, lane = t & 63, mr = lane & 15, q = lane >> 4;
  {
    int row = t >> 5, c2 = (t & 31) * 2;
    float2 fv = *(const float2*)&fea[(size_t)(g16 + row)*64 + c2];
    *(unsigned int*)&c.feaS[row][c2] = f2bf2(fv.x, fv.y);
  }
  c.bsc[t] = bias_c[h*512 + t];
  __syncthreads();
  {
    int n0w = w * 64;
    short8 a0 = *(const short8*)&c.feaS[mr][q*8];
    short8 a1 = *(const short8*)&c.feaS[mr][32 + q*8];
    #pragma unroll
    for (int nt = 0; nt < 4; ++nt) {
      int n = n0w + nt*16 + mr;
      const unsigned short* bp = WcryT + (size_t)(h*512 + n)*64 + q*8;
      short8 b0 = *(const short8*)bp;
      short8 b1 = *(const short8*)(bp + 32);
      f32x4 z = {0.f, 0.f, 0.f, 0.f};
      z = __builtin_amdgcn_mfma_f32_16x16x32_bf16(a0, b0, z, 0, 0, 0);
      z = __builtin_amdgcn_mfma_f32_16x16x32_bf16(a1, b1, z, 0, 0, 0);
      float bb = c.bsc[n];
      #pragma unroll
      for (int r = 0; r < 4; ++r)
        c.PQh[q*4 + r][n] = f2bf((z[r] + bb) * LOG2E_);
    }
  }
  __syncthreads();
  {
    int i = t >> 5, c0 = (t & 31) * 8;
    float s = 0.f;
    #pragma unroll
    for (int cc = c0; cc < c0+8; ++cc)
      s = fmaf(selu_t(bf2f(c.PQh[i][cc])), cg_W2[h*HID_ + cc], s);
    c.gred[i][t & 31] = s;
  }
  __syncthreads();
  if (t < 16) {
    float sg = 0.f;
    #pragma unroll
    for (int u = 0; u < 32; ++u) sg += c.gred[t][u];
    sg += cg_b2[h];
    float m = sg;
    #pragma unroll
    for (int s = 1; s < 16; s <<= 1) m = fmaxf(m, __shfl_xor(m, s, 16));
    float x = __powf(wts[g16 + t], c_pow[h]) * __expf(sg - m);
    float d = x;
    #pragma unroll
    for (int s = 1; s < 16; s <<= 1) d += __shfl_xor(d, s, 16);
    d += 1e-10f;
    float a = x / d;
    c.attnL[t] = a;
    float sa = a;
    #pragma unroll
    for (int s = 1; s < 16; s <<= 1) sa += __shfl_xor(sa, s, 16);
    if (t == 0) c.sumatS = sa;
  }
  {
    int i = t >> 5, c0 = (t & 31) * 8;
    #pragma unroll
    for (int cc = c0; cc < c0+8; cc += 2) {
      unsigned int pk = f2bf2(selu_t(bf2f(c.PQh[i][256 + cc])),
                              selu_t(bf2f(c.PQh[i][256 + cc + 1])));
      *(unsigned int*)&c.hidc[i][cc] = pk;
    }
  }
  __syncthreads();
  if (w < 4) {
    f32x4 acc = {0.f, 0.f, 0.f, 0.f};
    #pragma unroll
    for (int kc = 0; kc < 8; ++kc) {
      short8 a = *(const short8*)&c.hidc[mr][kc*32 + q*8];
      short8 b = *(const short8*)&W2cT[((size_t)h*64 + w*16 + mr)*HID_ + kc*32 + q*8];
      acc = __builtin_amdgcn_mfma_f32_16x16x32_bf16(a, b, acc, 0, 0, 0);
    }
    float p = 0.f;
    #pragma unroll
    for (int r = 0; r < 4; ++r) p = fmaf(c.attnL[q*4+r], acc[r], p);
    p += __shfl_xor(p, 16);
    p += __shfl_xor(p, 32);
    if (q == 0) {
      int f = w*16 + mr;
      atomicAdd(&out[(size_t)g*64 + f],
                (p + cm_b2[h*F_ + f]*c.sumatS) * (1.f/(float)H_));
    }
  }
}

// ---------------------------------------------------------------------------
// Whole network after prep: grid (G_,H_)=768 blocks, 512 threads. Each block
// runs its (g,h) slice of all 3 layers + cry head h; per-graph 3-block
// barriers between layers. LDS 33.5KB + VGPR<=64 -> 4 blk/CU -> capacity
// 1024 >= 768, all co-resident.
// ---------------------------------------------------------------------------
__global__ __launch_bounds__(512, 8) void net_fused(
    const float* __restrict__ fea0, float* __restrict__ fea1,
    float* __restrict__ fea2, float* __restrict__ fea3,
    const unsigned short* __restrict__ WcatT, const float* __restrict__ bias_e,
    const unsigned short* __restrict__ W2mT, const float* __restrict__ mg_W2,
    const float* __restrict__ mg_b2, const float* __restrict__ m_pow,
    const float* __restrict__ mm_b2,
    const unsigned short* __restrict__ WcryT, const float* __restrict__ bias_c,
    const unsigned short* __restrict__ W2cT, const float* __restrict__ cg_W2,
    const float* __restrict__ cg_b2, const float* __restrict__ cm_b2,
    const float* __restrict__ c_pow,
    const float* __restrict__ wts, float* __restrict__ out,
    unsigned int* __restrict__ cnt) {
  __shared__ __align__(16) NetSmem sm;
  int t = threadIdx.x;
  int g = blockIdx.x, g16 = g*16;
  int h = blockIdx.y;

  do_layer(sm, t, g16, h, 0, fea0, fea1, WcatT, bias_e, W2mT, mg_W2, mg_b2, m_pow, mm_b2, wts);
  graph_barrier(&cnt[g*4 + 0], t);
  do_layer(sm, t, g16, h, 1, fea1, fea2, WcatT, bias_e, W2mT, mg_W2, mg_b2, m_pow, mm_b2, wts);
  graph_barrier(&cnt[g*4 + 1], t);
  do_layer(sm, t, g16, h, 2, fea2, fea3, WcatT, bias_e, W2mT, mg_W2, mg_b2, m_pow, mm_b2, wts);
  graph_barrier(&cnt[g*4 + 2], t);
  do_cry(sm, t, g, h, fea3, WcryT, bias_c, W2cT, cg_W2, cg_b2, cm_b2, c_pow, wts, out);
}

extern "C" void kernel_launch(void* const* d_in, const int* in_sizes, int n_in,
                              void* d_out, int out_size, void* d_ws, size_t ws_size,
                              hipStream_t stream) {
  const float* elem_weights = (const float*)d_in[0];
  const float* elem_fea_in  = (const float*)d_in[1];
  const float* W_init = (const float*)d_in[2];
  const float* b_init = (const float*)d_in[3];
  const float* mg_W1  = (const float*)d_in[4];
  const float* mg_b1  = (const float*)d_in[5];
  const float* mg_W2  = (const float*)d_in[6];
  const float* mg_b2  = (const float*)d_in[7];
  const float* mm_W1  = (const float*)d_in[8];
  const float* mm_b1  = (const float*)d_in[9];
  const float* mm_W2  = (const float*)d_in[10];
  const float* mm_b2  = (const float*)d_in[11];
  const float* m_pow  = (const float*)d_in[12];
  const float* cg_W1  = (const float*)d_in[13];
  const float* cg_b1  = (const float*)d_in[14];
  const float* cg_W2  = (const float*)d_in[15];
  const float* cg_b2  = (const float*)d_in[16];
  const float* cm_W1  = (const float*)d_in[17];
  const float* cm_b1  = (const float*)d_in[18];
  const float* cm_W2  = (const float*)d_in[19];
  const float* cm_b2  = (const float*)d_in[20];
  const float* c_pow  = (const float*)d_in[21];
  float* out = (float*)d_out;

  float* ws = (float*)d_ws;
  float* feaA  = ws;                                   // init embed output
  float* feaB  = feaA + (size_t)N_*F_;                 // layer outputs (pre-zeroed)
  float* feaC  = feaB + (size_t)N_*F_;
  float* feaD  = feaC + (size_t)N_*F_;
  unsigned short* WcatT = (unsigned short*)(feaD + (size_t)N_*F_);  // 9*1024*64
  unsigned short* W2mT  = WcatT + (size_t)9*1024*64;                // 9*64*256
  unsigned short* WcryT = W2mT  + (size_t)9*64*256;                 // 1536*64
  unsigned short* W2cT  = WcryT + (size_t)1536*64;                  // 3*64*256
  float* bias_e = (float*)(W2cT + (size_t)3*64*256);                // 9216
  float* bias_c = bias_e + 9216;                                    // 1536
  unsigned int* cnt = (unsigned int*)(bias_c + 1536);               // 1024

  prep_init_all<<<256 + N_/4, 256, 0, stream>>>(
      mg_W1, mm_W1, mm_W2, cg_W1, cm_W1, cm_W2,
      mg_b1, mm_b1, cg_b1, cm_b1,
      WcatT, W2mT, WcryT, W2cT, bias_e, bias_c,
      out, feaB,
      elem_fea_in, W_init, b_init, elem_weights, feaA, cnt);

  net_fused<<<dim3(G_, H_), 512, 0, stream>>>(
      feaA, feaB, feaC, feaD,
      WcatT, bias_e, W2mT, mg_W2, mg_b2, m_pow, mm_b2,
      WcryT, bias_c, W2cT, cg_W2, cg_b2, cm_b2, c_pow,
      elem_weights, out, cnt);
}

// Round 9
// 235.402 us; speedup vs baseline: 2.9517x; 2.9517x over previous
//
#include <hip/hip_runtime.h>
#include <hip/hip_bf16.h>

#define G_ 256
#define K_ 16
#define L_ 3
#define H_ 3
#define F_ 64
#define EMB_ 200
#define HID_ 256
#define N_ (G_*K_)

typedef __attribute__((ext_vector_type(8))) short short8;
typedef __attribute__((ext_vector_type(4))) float f32x4;

#define SELU_S 1.0507009873554804934193349852946f
#define SELU_SA (1.0507009873554804934193349852946f*1.6732632423543772848170429916717f)
#define LOG2E_ 1.4426950408889634073599246810019f
#define SLN2_ (SELU_S*0.69314718055994530941723212145818f)

__device__ __forceinline__ float exp2_fast(float x) {
#if __has_builtin(__builtin_amdgcn_exp2f)
  return __builtin_amdgcn_exp2f(x);
#else
  return __exp2f(x);
#endif
}

// selu on t = x*log2(e); used in cry_fused only (proven there since R1;
// twice-measured regression when used in edge_fused hot loops - do not move).
__device__ __forceinline__ float selu_t(float t) {
  float tn = fminf(t, 0.f), tp = fmaxf(t, 0.f);
  return fmaf(SELU_SA, exp2_fast(tn), fmaf(SLN2_, tp, -SELU_SA));
}

__device__ __forceinline__ float selu_f(float x) {
  float e = __expf(x);
  float neg = fmaf(SELU_SA, e, -SELU_SA);
  float pos = SELU_S * x;
  return x > 0.f ? pos : neg;
}

__device__ __forceinline__ unsigned short f2bf(float x) {
  __hip_bfloat16 h = __float2bfloat16(x);
  return *reinterpret_cast<unsigned short*>(&h);
}

__device__ __forceinline__ unsigned int f2bf2(float a, float b) {
  float2 t; t.x = a; t.y = b;
  __hip_bfloat162 h = __float22bfloat162_rn(t);
  return *reinterpret_cast<unsigned int*>(&h);
}

__device__ __forceinline__ float bf2f(unsigned short u) {
  union { unsigned int i; float f; } v;
  v.i = ((unsigned int)u) << 16;
  return v.f;
}

// One kernel: blocks 0..255 do weight transposes/bias folding/out+fea zeroing
// (grid-stride over 256 blocks); blocks 256..1279 do init_embed, 4 nodes each.
__global__ __launch_bounds__(256) void prep_init_all(
    const float* __restrict__ mg_W1, const float* __restrict__ mm_W1,
    const float* __restrict__ mm_W2, const float* __restrict__ cg_W1,
    const float* __restrict__ cm_W1, const float* __restrict__ cm_W2,
    const float* __restrict__ mg_b1, const float* __restrict__ mm_b1,
    const float* __restrict__ cg_b1, const float* __restrict__ cm_b1,
    unsigned short* __restrict__ WcatT, unsigned short* __restrict__ W2mT,
    unsigned short* __restrict__ WcryT, unsigned short* __restrict__ W2cT,
    float* __restrict__ bias_e, float* __restrict__ bias_c,
    float* __restrict__ out0, float* __restrict__ feaZ,
    const float* __restrict__ fea_in, const float* __restrict__ W_init,
    const float* __restrict__ b_init, const float* __restrict__ wts,
    float* __restrict__ feaA) {
  int bid = blockIdx.x, tid = threadIdx.x;
  if (bid >= 256) {
    // ---- init_embed: 4 nodes per block ----
    __shared__ float row[4][EMB_];
    int sub = tid >> 6, j = tid & 63;
    int n = (bid - 256) * 4 + sub;
    for (int k = j; k < EMB_; k += 64) row[sub][k] = fea_in[(size_t)n*EMB_ + k];
    __syncthreads();
    if (j < F_-1) {
      float s = b_init[j];
      for (int k = 0; k < EMB_; ++k) s = fmaf(row[sub][k], W_init[k*(F_-1) + j], s);
      feaA[(size_t)n*F_ + j] = s;
    } else {
      feaA[(size_t)n*F_ + (F_-1)] = wts[n];
    }
    return;
  }
  int gt = bid*256 + tid, GT = 256*256;
  for (int idx = gt; idx < 9*1024*64; idx += GT) {      // WcatT[lh][n][k]
    int lh = idx >> 16, n = (idx >> 6) & 1023, k = idx & 63;
    const float* W = (n < 512) ? mg_W1 : mm_W1;
    int nn = n & 511;
    int r = (nn < 256) ? k : (64 + k);
    WcatT[idx] = f2bf(W[(size_t)lh*(2*F_*HID_) + r*HID_ + (nn & 255)]);
  }
  for (int idx = gt; idx < 9*64*256; idx += GT) {       // W2mT[lh][f][k]
    int lh = idx >> 14, f = (idx >> 8) & 63, k = idx & 255;
    W2mT[idx] = f2bf(mm_W2[(size_t)lh*(HID_*F_) + k*F_ + f]);
  }
  for (int idx = gt; idx < 1536*64; idx += GT) {        // WcryT[n][k]
    int n = idx >> 6, k = idx & 63;
    int hh = n >> 9, r = n & 511;
    float v = (r < 256) ? cg_W1[(size_t)hh*F_*HID_ + k*HID_ + r]
                        : cm_W1[(size_t)hh*F_*HID_ + k*HID_ + (r - 256)];
    WcryT[idx] = f2bf(v);
  }
  for (int idx = gt; idx < 3*64*256; idx += GT) {       // W2cT[h][f][k]
    int hh = idx >> 14, f = (idx >> 8) & 63, k = idx & 255;
    W2cT[idx] = f2bf(cm_W2[(size_t)hh*HID_*F_ + k*F_ + f]);
  }
  for (int idx = gt; idx < 9216 + 1536 + G_*F_; idx += GT) {  // biases + out zero
    if (idx < 9216) {
      int l = idx / 3072, c = idx - l*3072;
      int hh = c >> 10, cc = c & 1023;
      int lh = l*H_ + hh;
      float v = 0.f;
      if (cc < 256) v = mg_b1[lh*HID_ + cc];
      else if (cc >= 512 && cc < 768) v = mm_b1[lh*HID_ + (cc - 512)];
      bias_e[idx] = v;
    } else if (idx < 9216 + 1536) {
      int c = idx - 9216;
      int hh = c >> 9, cc = c & 511;
      bias_c[c] = (cc < 256) ? cg_b1[hh*HID_ + cc] : cm_b1[hh*HID_ + (cc - 256)];
    } else {
      out0[idx - 9216 - 1536] = 0.f;
    }
  }
  // zero fea buffers B,C,D (residual accumulation bases), float4 stores
  float4 z4; z4.x = 0.f; z4.y = 0.f; z4.z = 0.f; z4.w = 0.f;
  for (int idx = gt; idx < (3*N_*F_)/4; idx += GT)
    ((float4*)feaZ)[idx] = z4;
}

// ---------------------------------------------------------------------------
// Fused edge phase, 512 threads, grid (G_, H_).
// P0-P4: exact R3 proven code (selu_f, unscaled bf16 PQs). P5: adds the
// residual cur on the h==0 block (fea_nxt pre-zeroed; copy kernel eliminated).
// ---------------------------------------------------------------------------
__global__ __launch_bounds__(512, 4) void edge_fused(
    const float* __restrict__ fea, const unsigned short* __restrict__ WcatT,
    const float* __restrict__ bias_e, const unsigned short* __restrict__ W2T,
    const float* __restrict__ mg_W2, const float* __restrict__ mg_b2,
    const float* __restrict__ m_pow, const float* __restrict__ mm_b2,
    const float* __restrict__ wts, float* __restrict__ fea_nxt, int l) {
  __shared__ __align__(16) unsigned short feaS[16][72];
  __shared__ __align__(16) unsigned short PQs[16][520];
  __shared__ __align__(16) unsigned short HbarS[16][264];
  __shared__ float bs[512];
  __shared__ float w2g[256];
  __shared__ float gred[240][2];
  __shared__ float gateA[240];
  __shared__ float sumat[16];
  __shared__ float wp[16];
  int t = threadIdx.x;
  int g = blockIdx.x, g16 = g * 16;
  int h = blockIdx.y, lh = l*H_ + h;
  const unsigned short* Wlh = WcatT + (size_t)lh*1024*64;
  const float* biaslh = bias_e + (size_t)l*3072 + h*1024;
  int w = t >> 6, lane = t & 63, mr = lane & 15, q = lane >> 4;

  // P0: stage fea (bf16), gate bias, gate-W2
  {
    int row = t >> 5, c2 = (t & 31) * 2;
    float2 fv = *(const float2*)&fea[(size_t)(g16 + row)*64 + c2];
    *(unsigned int*)&feaS[row][c2] = f2bf2(fv.x, fv.y);
  }
  bs[t] = biaslh[t];
  if (t < 256) w2g[t] = mg_W2[lh*HID_ + t];
  __syncthreads();

  // P1: gate-half PQ GEMM (8 waves x 64 cols)
  {
    int n0w = w * 64;
    short8 a0 = *(const short8*)&feaS[mr][q*8];
    short8 a1 = *(const short8*)&feaS[mr][32 + q*8];
    #pragma unroll
    for (int nt = 0; nt < 4; ++nt) {
      int n = n0w + nt*16 + mr;
      const unsigned short* bp = Wlh + (size_t)n*64 + q*8;
      short8 b0 = *(const short8*)bp;
      short8 b1 = *(const short8*)(bp + 32);
      f32x4 z = {0.f, 0.f, 0.f, 0.f};
      z = __builtin_amdgcn_mfma_f32_16x16x32_bf16(a0, b0, z, 0, 0, 0);
      z = __builtin_amdgcn_mfma_f32_16x16x32_bf16(a1, b1, z, 0, 0, 0);
      float bb = bs[n];
      #pragma unroll
      for (int r = 0; r < 4; ++r)
        PQs[q*4 + r][n] = f2bf(z[r] + bb);
    }
  }
  __syncthreads();

  // P2: gate dot (480 thr) + wp precompute + msg bias reload
  {
    float nb = biaslh[512 + t];
    if (t < 480) {
      int e = t >> 1, half = t & 1;
      int i = e / 15, jj = e - i*15;
      int j = (jj < i) ? jj : jj + 1;
      float s = 0.f;
      #pragma unroll
      for (int u = 0; u < 16; ++u) {
        int c = half*8 + u*16;
        short8 pv = *(const short8*)&PQs[i][c];
        short8 qv = *(const short8*)&PQs[j][256 + c];
        #pragma unroll
        for (int r = 0; r < 8; ++r) {
          float hv = selu_f(bf2f((unsigned short)pv[r]) + bf2f((unsigned short)qv[r]));
          s = fmaf(hv, w2g[c + r], s);
        }
      }
      gred[e][half] = s;
    } else if (t < 496) {
      wp[t - 480] = __powf(wts[g16 + (t - 480)], m_pow[lh]);
    }
    bs[t] = nb;
  }
  __syncthreads();

  // P3: msg-half PQ GEMM (overwrite PQs) + softmax (t<16)
  {
    int n0w = w * 64;
    short8 a0 = *(const short8*)&feaS[mr][q*8];
    short8 a1 = *(const short8*)&feaS[mr][32 + q*8];
    #pragma unroll
    for (int nt = 0; nt < 4; ++nt) {
      int n = n0w + nt*16 + mr;
      const unsigned short* bp = Wlh + (size_t)(512 + n)*64 + q*8;
      short8 b0 = *(const short8*)bp;
      short8 b1 = *(const short8*)(bp + 32);
      f32x4 z = {0.f, 0.f, 0.f, 0.f};
      z = __builtin_amdgcn_mfma_f32_16x16x32_bf16(a0, b0, z, 0, 0, 0);
      z = __builtin_amdgcn_mfma_f32_16x16x32_bf16(a1, b1, z, 0, 0, 0);
      float bb = bs[n];
      #pragma unroll
      for (int r = 0; r < 4; ++r)
        PQs[q*4 + r][n] = f2bf(z[r] + bb);
    }
  }
  if (t < 16) {
    int i = t;
    float b2v = mg_b2[lh];
    float gl[15];
    float m = -1e30f;
    #pragma unroll
    for (int jj = 0; jj < 15; ++jj) {
      float v = gred[i*15 + jj][0] + gred[i*15 + jj][1] + b2v;
      gl[jj] = v; m = fmaxf(m, v);
    }
    float den = 0.f;
    #pragma unroll
    for (int jj = 0; jj < 15; ++jj) {
      int j = (jj < i) ? jj : jj + 1;
      float x = wp[j] * __expf(gl[jj] - m);
      gl[jj] = x; den += x;
    }
    den += 1e-10f;
    float sa = 0.f;
    #pragma unroll
    for (int jj = 0; jj < 15; ++jj) {
      float a = gl[jj] / den; gateA[i*15 + jj] = a; sa += a;
    }
    sumat[i] = sa;
  }
  __syncthreads();

  // P4: Hbar[i][k] = sum_j attn[i,j]*selu(P[i][k]+Q[j][k]); f32 accum, bf16 out.
  {
    int i = t >> 5, k0 = (t & 31) * 8;
    short8 pv = *(const short8*)&PQs[i][k0];
    float pf[8];
    #pragma unroll
    for (int r = 0; r < 8; ++r) pf[r] = bf2f((unsigned short)pv[r]);
    float hb[8] = {0.f, 0.f, 0.f, 0.f, 0.f, 0.f, 0.f, 0.f};
    for (int jj = 0; jj < 15; ++jj) {
      int j = (jj < i) ? jj : jj + 1;
      float a = gateA[i*15 + jj];
      short8 qv = *(const short8*)&PQs[j][256 + k0];
      #pragma unroll
      for (int r = 0; r < 8; ++r) {
        float hv = selu_f(pf[r] + bf2f((unsigned short)qv[r]));
        hb[r] = fmaf(a, hv, hb[r]);
      }
    }
    unsigned int hpk[4];
    #pragma unroll
    for (int r2 = 0; r2 < 4; ++r2) hpk[r2] = f2bf2(hb[2*r2], hb[2*r2+1]);
    *(short8*)&HbarS[i][k0] = *reinterpret_cast<short8*>(hpk);
  }
  __syncthreads();

  // P5: out = Hbar[16x256] @ W2m[256x64] on waves 0..3; epilogue adds
  // bias*sumat, /3, and (h==0 only) the residual cur.
  if (w < 4) {
    const unsigned short* W2lh = W2T + (size_t)lh*64*256;
    f32x4 acc = {0.f, 0.f, 0.f, 0.f};
    #pragma unroll
    for (int kc = 0; kc < 8; ++kc) {
      short8 a = *(const short8*)&HbarS[mr][kc*32 + q*8];
      short8 b = *(const short8*)&W2lh[(size_t)(w*16 + mr)*256 + kc*32 + q*8];
      acc = __builtin_amdgcn_mfma_f32_16x16x32_bf16(a, b, acc, 0, 0, 0);
    }
    int f = w*16 + mr;
    float b2 = mm_b2[lh*F_ + f];
    #pragma unroll
    for (int r = 0; r < 4; ++r) {
      int i = q*4 + r;
      float val = (acc[r] + b2*sumat[i]) * (1.f/3.f);
      if (h == 0) val += fea[(size_t)(g16 + i)*64 + f];
      atomicAdd(&fea_nxt[(size_t)(g16 + i)*64 + f], val);
    }
  }
}

// ---------------------------------------------------------------------------
// Crystal phase: one head per block, grid (G_, H_). atomicAdd into out
// (zeroed in prep). Exp2-domain pre-acts (R1, measured-passing).
// ---------------------------------------------------------------------------
__global__ __launch_bounds__(256) void cry_fused(
    const float* __restrict__ fea, const unsigned short* __restrict__ WcryT,
    const float* __restrict__ bias_c, const unsigned short* __restrict__ W2cT,
    const float* __restrict__ cg_W2, const float* __restrict__ cg_b2,
    const float* __restrict__ cm_b2, const float* __restrict__ c_pow,
    const float* __restrict__ wts, float* __restrict__ out) {
  __shared__ __align__(16) unsigned short feaS[16][72];
  __shared__ float PQh[16][520];
  __shared__ float bsc[512];
  __shared__ float gred[16][18];
  __shared__ float attnL[16];
  __shared__ float sumatS;
  __shared__ __align__(16) unsigned short hidc[16][264];
  int t = threadIdx.x;
  int g = blockIdx.x, g16 = g*16, h = blockIdx.y;
  {
    int row = t >> 4, c4 = (t & 15) * 4;
    float4 fv = *(const float4*)&fea[(size_t)(g16 + row)*64 + c4];
    *(unsigned int*)&feaS[row][c4]   = f2bf2(fv.x, fv.y);
    *(unsigned int*)&feaS[row][c4+2] = f2bf2(fv.z, fv.w);
  }
  bsc[t] = bias_c[h*512 + t];
  bsc[256 + t] = bias_c[h*512 + 256 + t];
  int w = t >> 6, lane = t & 63, mr = lane & 15, q = lane >> 4;
  __syncthreads();
  {
    int n0w = w * 128;
    short8 a0 = *(const short8*)&feaS[mr][q*8];
    short8 a1 = *(const short8*)&feaS[mr][32 + q*8];
    #pragma unroll
    for (int nt = 0; nt < 8; ++nt) {
      int n = n0w + nt*16 + mr;
      const unsigned short* bp = WcryT + (size_t)(h*512 + n)*64 + q*8;
      short8 b0 = *(const short8*)bp;
      short8 b1 = *(const short8*)(bp + 32);
      f32x4 z = {0.f, 0.f, 0.f, 0.f};
      z = __builtin_amdgcn_mfma_f32_16x16x32_bf16(a0, b0, z, 0, 0, 0);
      z = __builtin_amdgcn_mfma_f32_16x16x32_bf16(a1, b1, z, 0, 0, 0);
      float bb = bsc[n];
      #pragma unroll
      for (int r = 0; r < 4; ++r)
        PQh[q*4 + r][n] = (z[r] + bb) * LOG2E_;
    }
  }
  __syncthreads();
  {
    int i = t >> 4, c0 = (t & 15) * 16;
    float s = 0.f;
    #pragma unroll
    for (int c = c0; c < c0+16; ++c)
      s = fmaf(selu_t(PQh[i][c]), cg_W2[h*HID_ + c], s);
    gred[i][t & 15] = s;
  }
  __syncthreads();
  if (t < 16) {
    float sg = 0.f;
    #pragma unroll
    for (int u2 = 0; u2 < 16; ++u2) sg += gred[t][u2];
    gred[t][16] = sg + cg_b2[h];
  }
  __syncthreads();
  if (t == 0) {
    float pw = c_pow[h];
    float m = -1e30f;
    #pragma unroll
    for (int i = 0; i < 16; ++i) m = fmaxf(m, gred[i][16]);
    float den = 0.f; float v[16];
    #pragma unroll
    for (int i = 0; i < 16; ++i) {
      float x = __powf(wts[g16+i], pw) * __expf(gred[i][16] - m);
      v[i] = x; den += x;
    }
    den += 1e-10f;
    float sa = 0.f;
    #pragma unroll
    for (int i = 0; i < 16; ++i) { float a = v[i]/den; attnL[i] = a; sa += a; }
    sumatS = sa;
  }
  {
    int i = t >> 4, c0 = (t & 15) * 16;
    #pragma unroll
    for (int c = c0; c < c0+16; c += 2) {
      unsigned int pk = f2bf2(selu_t(PQh[i][256 + c]), selu_t(PQh[i][256 + c + 1]));
      *(unsigned int*)&hidc[i][c] = pk;
    }
  }
  __syncthreads();
  f32x4 acc = {0.f, 0.f, 0.f, 0.f};
  #pragma unroll
  for (int kc = 0; kc < 8; ++kc) {
    short8 a = *(const short8*)&hidc[mr][kc*32 + q*8];
    short8 b = *(const short8*)&W2cT[((size_t)h*64 + w*16 + mr)*HID_ + kc*32 + q*8];
    acc = __builtin_amdgcn_mfma_f32_16x16x32_bf16(a, b, acc, 0, 0, 0);
  }
  float p = 0.f;
  #pragma unroll
  for (int r = 0; r < 4; ++r) p = fmaf(attnL[q*4+r], acc[r], p);
  // reduce across q (lanes mr, mr+16, mr+32, mr+48)
  p += __shfl_xor(p, 16);
  p += __shfl_xor(p, 32);
  if (q == 0) {
    int f = w*16 + mr;
    atomicAdd(&out[(size_t)g*64 + f],
              (p + cm_b2[h*F_ + f]*sumatS) * (1.f/(float)H_));
  }
}

extern "C" void kernel_launch(void* const* d_in, const int* in_sizes, int n_in,
                              void* d_out, int out_size, void* d_ws, size_t ws_size,
                              hipStream_t stream) {
  const float* elem_weights = (const float*)d_in[0];
  const float* elem_fea_in  = (const float*)d_in[1];
  const float* W_init = (const float*)d_in[2];
  const float* b_init = (const float*)d_in[3];
  const float* mg_W1  = (const float*)d_in[4];
  const float* mg_b1  = (const float*)d_in[5];
  const float* mg_W2  = (const float*)d_in[6];
  const float* mg_b2  = (const float*)d_in[7];
  const float* mm_W1  = (const float*)d_in[8];
  const float* mm_b1  = (const float*)d_in[9];
  const float* mm_W2  = (const float*)d_in[10];
  const float* mm_b2  = (const float*)d_in[11];
  const float* m_pow  = (const float*)d_in[12];
  const float* cg_W1  = (const float*)d_in[13];
  const float* cg_b1  = (const float*)d_in[14];
  const float* cg_W2  = (const float*)d_in[15];
  const float* cg_b2  = (const float*)d_in[16];
  const float* cm_W1  = (const float*)d_in[17];
  const float* cm_b1  = (const float*)d_in[18];
  const float* cm_W2  = (const float*)d_in[19];
  const float* cm_b2  = (const float*)d_in[20];
  const float* c_pow  = (const float*)d_in[21];
  float* out = (float*)d_out;

  float* ws = (float*)d_ws;
  float* feaA  = ws;                                   // init embed output
  float* feaB  = feaA + (size_t)N_*F_;                 // layer outputs (pre-zeroed)
  float* feaC  = feaB + (size_t)N_*F_;
  float* feaD  = feaC + (size_t)N_*F_;
  unsigned short* WcatT = (unsigned short*)(feaD + (size_t)N_*F_);  // 9*1024*64
  unsigned short* W2mT  = WcatT + (size_t)9*1024*64;                // 9*64*256
  unsigned short* WcryT = W2mT  + (size_t)9*64*256;                 // 1536*64
  unsigned short* W2cT  = WcryT + (size_t)1536*64;                  // 3*64*256
  float* bias_e = (float*)(W2cT + (size_t)3*64*256);                // 9216
  float* bias_c = bias_e + 9216;                                    // 1536

  prep_init_all<<<256 + N_/4, 256, 0, stream>>>(
      mg_W1, mm_W1, mm_W2, cg_W1, cm_W1, cm_W2,
      mg_b1, mm_b1, cg_b1, cm_b1,
      WcatT, W2mT, WcryT, W2cT, bias_e, bias_c,
      out, feaB,
      elem_fea_in, W_init, b_init, elem_weights, feaA);

  float* bufs[4] = {feaA, feaB, feaC, feaD};
  for (int l = 0; l < L_; ++l) {
    edge_fused<<<dim3(G_, H_), 512, 0, stream>>>(
        bufs[l], WcatT, bias_e, W2mT, mg_W2, mg_b2, m_pow, mm_b2,
        elem_weights, bufs[l+1], l);
  }

  cry_fused<<<dim3(G_, H_), 256, 0, stream>>>(
      bufs[3], WcryT, bias_c, W2cT, cg_W2, cg_b2, cm_b2, c_pow,
      elem_weights, out);
}